// Round 15
// baseline (339.668 us; speedup 1.0000x reference)
//
#include <hip/hip_runtime.h>
#include <hip/hip_bf16.h>
#include <math.h>

#define Hdim 1024
#define Bdim 32
#define Ldim 2048
#define Mtot (Bdim*Ldim)   // 65536

typedef __attribute__((ext_vector_type(8))) short short8v;
typedef __attribute__((ext_vector_type(4))) short short4v;
typedef __attribute__((ext_vector_type(16))) float floatx16;

static __device__ inline short f2bf(float f) {
    union { float f; unsigned u; } x; x.f = f;
    unsigned r = x.u + 0x7FFF + ((x.u >> 16) & 1);   // RNE
    return (short)(r >> 16);
}
static __device__ inline float bf2f(short s) {
    union { unsigned u; float f; } x; x.u = ((unsigned)(unsigned short)s) << 16;
    return x.f;
}

static __device__ inline float fast_tanh(float x) {
    float t = 2.0f * x;
    t = fminf(fmaxf(t, -30.0f), 30.0f);
    float e = __expf(t);
    return (e - 1.0f) / (e + 1.0f);
}

typedef __attribute__((address_space(1))) const void GVT;
typedef __attribute__((address_space(3))) void LVT;
static __device__ inline void gload_lds16(const void* g, void* l) {
    __builtin_amdgcn_global_load_lds((GVT*)g, (LVT*)l, 16, 0, 0);
}

// ---------------- Kernel 0a: enc f32 -> bf16 (one-time, BW-bound ~64us) ----------------
__global__ __launch_bounds__(256) void convert_enc_kernel(
    const float* __restrict__ enc, short* __restrict__ enc_bf)
{
    size_t i = ((size_t)blockIdx.x * 256 + threadIdx.x) * 8;
    float4 a = *(const float4*)(enc + i);
    float4 b = *(const float4*)(enc + i + 4);
    short8v o;
    o[0]=f2bf(a.x); o[1]=f2bf(a.y); o[2]=f2bf(a.z); o[3]=f2bf(a.w);
    o[4]=f2bf(b.x); o[5]=f2bf(b.y); o[6]=f2bf(b.z); o[7]=f2bf(b.w);
    *(short8v*)(enc_bf + i) = o;
}

// ---------------- Kernel 0b: W_e f32 -> compact bf16 [1024][1024] ----------------
__global__ __launch_bounds__(256) void convert_w_kernel(
    const float* __restrict__ attn_w, short* __restrict__ w_bf)
{
    int t = blockIdx.x * 256 + threadIdx.x;
    int o = t >> 7;
    int c = t & 127;
    const float* src = attn_w + (size_t)o * 2 * Hdim + Hdim + c * 8;
    float4 a = *(const float4*)(src);
    float4 b = *(const float4*)(src + 4);
    short8v v;
    v[0]=f2bf(a.x); v[1]=f2bf(a.y); v[2]=f2bf(a.z); v[3]=f2bf(a.w);
    v[4]=f2bf(b.x); v[5]=f2bf(b.y); v[6]=f2bf(b.z); v[7]=f2bf(b.w);
    *(short8v*)(w_bf + (size_t)o * Hdim + c * 8) = v;
}

// ---------------- Kernel 1: q[b][o] = hidden[b]·W_h[o] + bias[o] ----------------
__global__ __launch_bounds__(256) void qproj_kernel(
    const float* __restrict__ hidden, const float* __restrict__ attn_w,
    const float* __restrict__ attn_b, float* __restrict__ qbuf)
{
    int w = blockIdx.x * 4 + (threadIdx.x >> 6);
    int lane = threadIdx.x & 63;
    int o = w >> 5;
    int b = w & 31;
    const float* hrow = hidden + b * Hdim;
    const float* wrow = attn_w + (size_t)o * 2 * Hdim;
    float s = 0.f;
    #pragma unroll
    for (int i = 0; i < 16; i++) s += hrow[lane + i*64] * wrow[lane + i*64];
    s += __shfl_xor(s, 1);  s += __shfl_xor(s, 2);  s += __shfl_xor(s, 4);
    s += __shfl_xor(s, 8);  s += __shfl_xor(s, 16); s += __shfl_xor(s, 32);
    if (lane == 0) qbuf[b * Hdim + o] = s + attn_b[o];
}

// ---------------- Kernel 2: 32x32x16-MFMA GEMM + tanh + v-dot (r6 pipeline) ----
// Shape change: v_mfma_f32_32x32x16_bf16 halves LDS-read-bytes per FLOP and runs
// at 2382 vs 2075 TF. Per-wave 64x64 = 2x2 tiles of 32x32, acc 4x16 f32.
// A frag: row=l&31, k-half h=l>>5 (within-dot K-permute harmless). C/D: col=l&31,
// row=(reg&3)+8*(reg>>2)+4*h (HW-verified m74/m101). Swizzle: stage src chunk
// (l&3)^((l>>2)&3); read chunk (kk*2+h)^(l&3) -> <=2-way (free).
#define BM 128
#define BN 128
#define BK 32
#define NKT 32

__global__ __launch_bounds__(256, 4) void scores_kernel(
    const short* __restrict__ enc_bf,   // [Mtot][1024] bf16
    const short* __restrict__ w_bf,     // [1024][1024] bf16
    const float* __restrict__ qbuf,     // [B][H]
    const float* __restrict__ vvec,     // [H]
    float* __restrict__ spart)          // [8][Mtot]
{
    __shared__ short As[2][BM * BK];    // 2 x 8 KB
    __shared__ short Bs[2][BN * BK];    // 2 x 8 KB
    __shared__ float sred[BM][2];

    // XCD swizzle: 8 nblk sharers of one A-panel on one XCD. grid 4096 = 8*8*64.
    int hw = blockIdx.x;
    int xcd = hw & 7;
    int i5  = hw >> 3;
    int nblk  = i5 & 7;
    int mtile = xcd * 64 + (i5 >> 3);
    int m0 = mtile * BM;
    int n0 = nblk * BN;

    int tid  = threadIdx.x;
    int w    = tid >> 6;
    int l    = tid & 63;
    int wr = w >> 1, wc = w & 1;
    int r31 = l & 31;
    int h   = l >> 5;

    // staging: per operand, wave w covers rows [w*32, w*32+32), 2 gloads of 16 rows.
    // lane l -> row l>>2, LDS chunk l&3; source chunk = (l&3) ^ ((l>>2)&3) = (l&3)^(row&3)
    const short* agp = enc_bf + (size_t)(m0 + w*32 + (l >> 2)) * Hdim
                              + (((l & 3) ^ ((l >> 2) & 3)) * 8);
    const short* bgp = w_bf  + (size_t)(n0 + w*32 + (l >> 2)) * Hdim
                              + (((l & 3) ^ ((l >> 2) & 3)) * 8);
#define STAGE_A(bb, k0) do { \
    gload_lds16(agp + (k0),                      &As[bb][(w*32)      * BK]); \
    gload_lds16(agp + (k0) + 16*(size_t)Hdim,    &As[bb][(w*32 + 16) * BK]); \
} while (0)
#define STAGE_B(bb, k0) do { \
    gload_lds16(bgp + (k0),                      &Bs[bb][(w*32)      * BK]); \
    gload_lds16(bgp + (k0) + 16*(size_t)Hdim,    &Bs[bb][(w*32 + 16) * BK]); \
} while (0)

    // fragment reads: row/col = wr(wc)*64 + t*32 + r31; chunk c = (kk*2+h) ^ (l&3)
    int c0 = ((0*2 + h) ^ (l & 3)) * 8;   // kk=0
    int c1 = ((1*2 + h) ^ (l & 3)) * 8;   // kk=1
#define LDA(mi, cc) (*(const short8v*)(&As[cur][(wr*64 + (mi)*32 + r31) * BK + (cc)]))
#define LDB(ni, cc) (*(const short8v*)(&Bs[cur][(wc*64 + (ni)*32 + r31) * BK + (cc)]))

    floatx16 acc[2][2];
    #pragma unroll
    for (int i = 0; i < 2; i++)
        #pragma unroll
        for (int j = 0; j < 2; j++)
            #pragma unroll
            for (int e = 0; e < 16; e++) acc[i][j][e] = 0.f;

    // prologue
    STAGE_A(0, 0);
    STAGE_B(0, 0);
    __syncthreads();

    #pragma unroll 2
    for (int kt = 0; kt < NKT; kt++) {
        int cur = kt & 1;
        int nxt = cur ^ 1;
        if (kt < NKT - 1) {
            STAGE_A(nxt, (kt + 1) * BK);
            STAGE_B(nxt, (kt + 1) * BK);
        }
        short8v a0[2], a1[2], b0[2], b1[2];
        #pragma unroll
        for (int mi = 0; mi < 2; mi++) { a0[mi] = LDA(mi, c0); a1[mi] = LDA(mi, c1); }
        #pragma unroll
        for (int ni = 0; ni < 2; ni++) { b0[ni] = LDB(ni, c0); b1[ni] = LDB(ni, c1); }
        #pragma unroll
        for (int mi = 0; mi < 2; mi++)
            #pragma unroll
            for (int ni = 0; ni < 2; ni++) {
                acc[mi][ni] = __builtin_amdgcn_mfma_f32_32x32x16_bf16(a0[mi], b0[ni], acc[mi][ni], 0, 0, 0);
                acc[mi][ni] = __builtin_amdgcn_mfma_f32_32x32x16_bf16(a1[mi], b1[ni], acc[mi][ni], 0, 0, 0);
            }
        __syncthreads();
    }

    // ---- epilogue: tanh(proj + q) * v, reduce over this block's 128 cols ----
    // C/D: col = r31, row(reg,h) = (reg&3) + 8*(reg>>2) + 4*h  (within 32-tile)
    #pragma unroll
    for (int mi = 0; mi < 2; mi++) {
        float rs[16];
        #pragma unroll
        for (int reg = 0; reg < 16; reg++) rs[reg] = 0.f;
        #pragma unroll
        for (int ni = 0; ni < 2; ni++) {
            int o = n0 + wc*64 + ni*32 + r31;
            float vo = vvec[o];
            #pragma unroll
            for (int reg = 0; reg < 16; reg++) {
                int rloc = (reg & 3) + 8*(reg >> 2) + 4*h;    // 0..31 = b index
                float p = acc[mi][ni][reg] + qbuf[rloc * Hdim + o];
                rs[reg] += fast_tanh(p) * vo;
            }
        }
        #pragma unroll
        for (int reg = 0; reg < 16; reg++) {
            float s = rs[reg];
            s += __shfl_xor(s, 1); s += __shfl_xor(s, 2); s += __shfl_xor(s, 4);
            s += __shfl_xor(s, 8); s += __shfl_xor(s, 16);
            if (r31 == 0) {
                int r = wr*64 + mi*32 + (reg & 3) + 8*(reg >> 2) + 4*h;
                sred[r][wc] = s;
            }
        }
    }
    __syncthreads();
    if (tid < BM)
        spart[(size_t)nblk * Mtot + m0 + tid] = sred[tid][0] + sred[tid][1];
#undef STAGE_A
#undef STAGE_B
#undef LDA
#undef LDB
}

// ---------------- Kernel 3: reduce 8 partials + softmax over L (per b) ----------------
__global__ __launch_bounds__(256) void softmax_kernel(
    const float* __restrict__ spart,   // [8][Mtot], m = l*32+b
    float* __restrict__ attn)          // [B][L]
{
    int b = blockIdx.x;
    int t = threadIdx.x;
    __shared__ float rmax[4], rsum[4];
    float sv[8];
    float mx = -1e30f;
    #pragma unroll
    for (int i = 0; i < 8; i++) {
        int l = t + i * 256;
        int m = l * Bdim + b;
        float s = 0.f;
        #pragma unroll
        for (int p = 0; p < 8; p++) s += spart[(size_t)p * Mtot + m];
        sv[i] = s;
        mx = fmaxf(mx, s);
    }
    #pragma unroll
    for (int off = 1; off < 64; off <<= 1) mx = fmaxf(mx, __shfl_xor(mx, off));
    if ((t & 63) == 0) rmax[t >> 6] = mx;
    __syncthreads();
    mx = fmaxf(fmaxf(rmax[0], rmax[1]), fmaxf(rmax[2], rmax[3]));
    float sum = 0.f;
    #pragma unroll
    for (int i = 0; i < 8; i++) { sv[i] = __expf(sv[i] - mx); sum += sv[i]; }
    #pragma unroll
    for (int off = 1; off < 64; off <<= 1) sum += __shfl_xor(sum, off);
    if ((t & 63) == 0) rsum[t >> 6] = sum;
    __syncthreads();
    sum = rsum[0] + rsum[1] + rsum[2] + rsum[3];
    float inv = 1.f / sum;
    #pragma unroll
    for (int i = 0; i < 8; i++)
        attn[(size_t)b * Ldim + t + i * 256] = sv[i] * inv;
}

// ---------------- Kernel 4: context partials over L-chunks (bf16 enc) ----------------
__global__ __launch_bounds__(256) void context_part_kernel(
    const short* __restrict__ enc_bf,
    const float* __restrict__ attn,
    float* __restrict__ cpart)         // [64][B][H]
{
    int b = blockIdx.x & 31;
    int c = blockIdx.x >> 5;
    int t = threadIdx.x;
    float a0 = 0.f, a1 = 0.f, a2 = 0.f, a3 = 0.f;
    int l0 = c * 32;
    for (int i = 0; i < 32; i++) {
        int l = l0 + i;
        float a = attn[(size_t)b * Ldim + l];
        short4v e = *(const short4v*)(enc_bf + (size_t)(l * Bdim + b) * Hdim + t * 4);
        a0 += a * bf2f(e.x); a1 += a * bf2f(e.y);
        a2 += a * bf2f(e.z); a3 += a * bf2f(e.w);
    }
    float4 r; r.x = a0; r.y = a1; r.z = a2; r.w = a3;
    *(float4*)(cpart + ((size_t)c * Bdim + b) * Hdim + t * 4) = r;
}

// ---------------- Kernel 5: reduce context partials ----------------
__global__ __launch_bounds__(256) void context_reduce_kernel(
    const float* __restrict__ cpart, float* __restrict__ out)
{
    int idx = blockIdx.x * 256 + threadIdx.x;
    float s = 0.f;
    for (int c = 0; c < 64; c++) s += cpart[(size_t)c * (Bdim * Hdim) + idx];
    out[idx] = s;
}

extern "C" void kernel_launch(void* const* d_in, const int* in_sizes, int n_in,
                              void* d_out, int out_size, void* d_ws, size_t ws_size,
                              hipStream_t stream)
{
    const float* hidden = (const float*)d_in[0];
    const float* enc    = (const float*)d_in[1];   // (L,B,H), m = l*32+b
    const float* attn_w = (const float*)d_in[2];
    const float* attn_b = (const float*)d_in[3];
    const float* vvec   = (const float*)d_in[4];
    float* out = (float*)d_out;

    char* ws = (char*)d_ws;
    size_t off = 0;
    short* enc_bf = (short*)(ws + off); off += (size_t)Mtot * Hdim * 2;       // 134.2 MB
    short* w_bf   = (short*)(ws + off); off += (size_t)Hdim * Hdim * 2;       //   2.1 MB
    float* qbuf   = (float*)(ws + off); off += (size_t)Bdim * Hdim * 4;       //   0.13 MB
    float* spart  = (float*)(ws + off); off += (size_t)8 * Mtot * 4;          //   2.1 MB
    float* attnp  = (float*)(ws + off); off += (size_t)Mtot * 4;              //   0.26 MB
    float* cpart  = (float*)(ws + off);                                       //   8.4 MB

    convert_enc_kernel<<<32768, 256, 0, stream>>>(enc, enc_bf);
    convert_w_kernel<<<512, 256, 0, stream>>>(attn_w, w_bf);
    qproj_kernel<<<8192, 256, 0, stream>>>(hidden, attn_w, attn_b, qbuf);
    scores_kernel<<<4096, 256, 0, stream>>>(enc_bf, w_bf, qbuf, vvec, spart);
    softmax_kernel<<<Bdim, 256, 0, stream>>>(spart, attnp);
    context_part_kernel<<<2048, 256, 0, stream>>>(enc_bf, attnp, cpart);
    context_reduce_kernel<<<128, 256, 0, stream>>>(cpart, out);
}